// Round 16
// baseline (239.014 us; speedup 1.0000x reference)
//
#include <hip/hip_runtime.h>

// NSDE pricer, R18: critical-path trims on R17 — w0f hoisted, layer3 tree.
// R17: 152.6 us, VALUBusy 68.7% (busy ~105 us: ~55 trans floor + ~50 other),
// idle ~31% = dependent-chain latency at the 4-waves/SIMD occupancy cap
// (R16: not barriers; R8->R9: fewer waves loses). Shorten the chain:
//  1. W0 A-frags (step-invariant, 8 uint4 = 32 VGPR both nets) hoisted ONCE
//     above the step loop as register values -> removes the post-barrier
//     ds_read burst from every phase's critical path (+deletes 8 reads/step).
//     Bounded residency (~90 VGPR total, <128 budget at waves_per_eu(4)) --
//     unlike R5/R7's 128-VGPR w1f hoist that spilled.
//  2. Layer3 accumulation: 16-deep serial fma chain -> 4 independent per-nt
//     partials (interleave with MFMA/trans) + pairwise tree (chain 16 -> 6).
// Everything else identical to R17 (passed, absmax 1.0): layer1 via MFMA
// (sigma-permuted hidden, double-bf16 S/wS/wT), swapped-MFMA layer2, layer3
// r-fold (w2sum - 2*sum(w2*r)), lane-local + 2-shfl reduce, k=2/ln2 in
// weights, S/V register-carried, 2 block barriers/step, anti-LICM asm
// barrier, block 512 = 8 waves = 1 path, grid 512, waves_per_eu(4).

#define N_PATHS 512
#define N_STEPS 32
#define B_OPTS  64
#define HID     64

#define TANH_K 2.8853900817779268f   // 2/ln2: tanh(x) = 1 - 2/(2^(k*x)+1)

typedef __attribute__((ext_vector_type(8))) short bf16x8;   // 8 bf16 (4 VGPRs)
typedef __attribute__((ext_vector_type(4))) float f32x4;
typedef __attribute__((ext_vector_type(4))) unsigned u32x4;

__device__ __forceinline__ float tanh_from_scaled(float a) {
    // a = k*x already (k folded into weights). tanh = 1 - 2/(2^a + 1).
    float u = __builtin_amdgcn_exp2f(a);
    float r = __builtin_amdgcn_rcpf(u + 1.0f);
    return fmaf(-2.0f, r, 1.0f);
}

__device__ __forceinline__ float sig2r(float a) {
    // r = 1/(2^a + 1) in [0,1]; tanh(x) = 1 - 2r. rcp(inf)=0: exact sat.
    float u = __builtin_amdgcn_exp2f(a);
    return __builtin_amdgcn_rcpf(u + 1.0f);
}

__device__ __forceinline__ short f2bf(float f) {            // fp32 -> bf16 RNE
    union { float f; unsigned u; } c; c.f = f;
    unsigned u = c.u + 0x7FFFu + ((c.u >> 16) & 1u);
    return (short)(u >> 16);
}

__device__ __forceinline__ unsigned cvt_pk_bf16(float lo, float hi) {
    // packs lo -> [15:0], hi -> [31:16] as bf16 (RNE), single VALU op.
    unsigned r;
    asm("v_cvt_pk_bf16_f32 %0, %1, %2" : "=v"(r) : "v"(lo), "v"(hi));
    return r;
}

__device__ __forceinline__ void bsplit(float x, float& hi, float& lo) {
    // double-bf16 split: x = hi + lo with hi = bf16(x) (as fp32), lo residual.
    const unsigned u = cvt_pk_bf16(x, x);
    hi = __builtin_bit_cast(float, u << 16);
    lo = x - hi;
}

// One net: layer1 via MFMA-1 (w0f preloaded in regs) + tanh + pack; layer2
// MFMA-2 (A=k*W1 sigma-frags from LDS, B=h1, C=k*b1); layer3 lane-local
// r-dot (4 partials + tree) + 2-shfl reduce. Returns f for row nh, valid at
// ALL lanes.
__device__ __forceinline__ float mlp_one(
    int net, int q,
    bf16x8 svt,                                 // input frag (A-side zeros mask)
    const uint4 (&w0f)[4],                      // W0 A-frags, register-resident
    const float*  __restrict__ b0e,             // LDS, k*(b0+rf*w_rf), [4][64]
    const uint4*  __restrict__ w1p,             // LDS W1 frags (k*W1), lane-offset
    const float*  __restrict__ b1k,             // LDS, k*b1, [4][64]
    const float (&w2n)[4][4], float w2sum, float b2s)
{
    // Block LICM: nothing memory-derived carried across phases/steps
    // (R5/R7 lesson: hoisted LDS values spill to scratch -> 1.7 GB HBM).
    // w0f is exempt by design: passed as register VALUES (32 VGPR, bounded).
    asm volatile("" ::: "memory");
    // ---- W1 frags early: DS latency hides under MFMA-1 + layer1 trans ----
    uint4 wfr[8];
#pragma unroll
    for (int i = 0; i < 8; ++i) wfr[i] = w1p[(net * 8 + i) * 64];

    // ---- layer1 (MFMA pipe): preact[H=16mt+4q+r][row=nh] ----
    f32x4 c1[4];
#pragma unroll
    for (int mt = 0; mt < 4; ++mt) {
        f32x4 ci = *(const f32x4*)&b0e[net * 64 + mt * 16 + 4 * q];
        c1[mt] = __builtin_amdgcn_mfma_f32_16x16x32_bf16(
                     __builtin_bit_cast(bf16x8, w0f[mt]), svt, ci, 0, 0, 0);
    }
    // ---- tanh + pack directly into MFMA-2 B-frag order (sigma trick) ----
    u32x4 afr[2];
#pragma unroll
    for (int x = 0; x < 2; ++x) {
        afr[x][0] = cvt_pk_bf16(tanh_from_scaled(c1[2 * x][0]),
                                tanh_from_scaled(c1[2 * x][1]));
        afr[x][1] = cvt_pk_bf16(tanh_from_scaled(c1[2 * x][2]),
                                tanh_from_scaled(c1[2 * x][3]));
        afr[x][2] = cvt_pk_bf16(tanh_from_scaled(c1[2 * x + 1][0]),
                                tanh_from_scaled(c1[2 * x + 1][1]));
        afr[x][3] = cvt_pk_bf16(tanh_from_scaled(c1[2 * x + 1][2]),
                                tanh_from_scaled(c1[2 * x + 1][3]));
    }
    const bf16x8 h0 = __builtin_bit_cast(bf16x8, afr[0]);
    const bf16x8 h1 = __builtin_bit_cast(bf16x8, afr[1]);

    // ---- layer2+3: C[m=4q+r][n=nh]; 4 independent partials + tree ----
    float p[4];
#pragma unroll
    for (int nt = 0; nt < 4; ++nt) {
        f32x4 c = *(const f32x4*)&b1k[net * 64 + nt * 16 + 4 * q];  // b128 bcast
        c = __builtin_amdgcn_mfma_f32_16x16x32_bf16(
                __builtin_bit_cast(bf16x8, wfr[nt * 2 + 0]), h0, c, 0, 0, 0);
        c = __builtin_amdgcn_mfma_f32_16x16x32_bf16(
                __builtin_bit_cast(bf16x8, wfr[nt * 2 + 1]), h1, c, 0, 0, 0);
        float ps = 0.0f;
#pragma unroll
        for (int r = 0; r < 4; ++r)
            ps = fmaf(w2n[nt][r], sig2r(c[r]), ps);
        p[nt] = ps;
    }
    float s = ((p[0] + p[1]) + (p[2] + p[3])) + w2sum;
    s += __shfl_xor(s, 16);                      // reduce over q-groups
    s += __shfl_xor(s, 32);
    return s + b2s;
}

__global__ __launch_bounds__(512)
__attribute__((amdgpu_waves_per_eu(4)))
void nsde_kernel(
    const float* __restrict__ S0p, const float* __restrict__ Kp,
    const float* __restrict__ Tp,  const float* __restrict__ rfp,
    const float* __restrict__ Z1,  const float* __restrict__ Z2,
    const float* __restrict__ W0,  const float* __restrict__ b0,
    const float* __restrict__ W1,  const float* __restrict__ b1,
    const float* __restrict__ W2,  const float* __restrict__ b2,
    float* __restrict__ out, float* __restrict__ ws, int use_ws)
{
    const int tid  = threadIdx.x;
    const int wave = tid >> 6;                      // 0..7
    const int lane = tid & 63;
    const int q    = lane >> 4;
    const int nh   = lane & 15;
    const int t    = wave >> 1;                     // tile 0..3
    const int role = wave & 1;                      // 0: nets 0/2, 1: nets 1/3
    const int path = blockIdx.x;                    // one path per block
    const int row  = t * 16 + nh;                   // this lane's option row

    __shared__ uint4  w0a[1024];                    // W0 A-frags, 16 KB
    __shared__ uint4  w1f[2048];                    // k*W1 bf16 frags, 32 KB
    __shared__ __align__(16) float b0e[4 * 64];     // k*(b0 + rf*w_rf), f32
    __shared__ __align__(16) float b1k[4 * 64];     // k*b1, f32
    __shared__ float2 fx2[64];                      // phase-1 exchange [row]
    __shared__ float2 gx2[64];                      // phase-2 exchange

    const float rf = rfp[0];

    // ---- one-time staging: b0e, b1k ----
    if (tid < 256) {
        const int net = tid >> 6, kk = tid & 63;
        b0e[tid] = TANH_K * fmaf(rf, W0[net * 256 + 128 + kk], b0[tid]);
        b1k[tid] = TANH_K * b1[tid];
    }

    // ---- one-time staging: W0 A-frags (double-bf16 wS, wT; single wV) ----
    // frag (net,mt) lane(q0,nh0): q0==0 slots: wShi,wShi | wSlo,wV | wThi,wThi
    // | wTlo,0 for hidden H = 16mt + nh0; all other lanes zero (this zeroing
    // is the k-slot mask -- B side needs no masking).
#pragma unroll
    for (int it = 0; it < 2; ++it) {
        const int f   = it * 512 + tid;             // 0..1023
        const int ls  = f & 63;
        const int mt  = (f >> 6) & 3;
        const int nts = f >> 8;                     // net
        uint4 fr = {0u, 0u, 0u, 0u};
        if ((ls >> 4) == 0) {
            const int H = mt * 16 + (ls & 15);
            const float wS = TANH_K * W0[nts * 256 + 0   + H];
            const float wV = TANH_K * W0[nts * 256 + 64  + H];
            const float wT = TANH_K * W0[nts * 256 + 192 + H];
            const unsigned sh = (unsigned)(unsigned short)f2bf(wS);
            const float shf   = __builtin_bit_cast(float, sh << 16);
            const unsigned th = (unsigned)(unsigned short)f2bf(wT);
            const float thf   = __builtin_bit_cast(float, th << 16);
            fr.x = sh | (sh << 16);
            fr.y = (unsigned)(unsigned short)f2bf(wS - shf)
                 | ((unsigned)(unsigned short)f2bf(wV) << 16);
            fr.z = th | (th << 16);
            fr.w = (unsigned)(unsigned short)f2bf(wT - thf);
        }
        w0a[f] = fr;
    }

    // ---- one-time staging: k*W1 -> LDS bf16 frags, sigma k-ordering ----
    // frag f: nh=f&15, q=(f>>4)&3, kh=(f>>6)&1, nt=(f>>7)&3, net=(f>>9)&3
    // element j holds k*W1[H = 16*(2kh + (j>>2)) + 4q + (j&3)][16nt + nh].
#pragma unroll
    for (int it = 0; it < 4; ++it) {
        const int f   = it * 512 + tid;
        const int fnh = f & 15;
        const int fq  = (f >> 4) & 3;
        const int fkh = (f >> 6) & 1;
        const int fnt = (f >> 7) & 3;
        const int fnet= (f >> 9) & 3;
        bf16x8 fr;
#pragma unroll
        for (int j = 0; j < 8; ++j) {
            const int H = 16 * (2 * fkh + (j >> 2)) + 4 * fq + (j & 3);
            fr[j] = f2bf(TANH_K * W1[fnet * 4096 + H * 64 + fnt * 16 + fnh]);
        }
        w1f[f] = __builtin_bit_cast(uint4, fr);
    }

    // ---- per-lane constants (only this wave's two nets) ----
    const float dta  = Tp[row] * (1.0f / N_STEPS);
    const float sqdt = sqrtf(dta);
    const int netA = role;                          // phase-1 net
    const int netB = role + 2;                      // phase-2 net

    float w2nA[4][4], w2nB[4][4];                   // -2*W2 at hid=16nt+4q+r
    float w2sA = 0.0f, w2sB = 0.0f;                 // per-lane partial sum(W2)
#pragma unroll
    for (int nt = 0; nt < 4; ++nt)
#pragma unroll
        for (int r = 0; r < 4; ++r) {
            const int hid = nt * 16 + 4 * q + r;
            const float a2  = W2[netA * 64 + hid];
            const float b2v = W2[netB * 64 + hid];
            w2nA[nt][r] = -2.0f * a2;  w2sA += a2;
            w2nB[nt][r] = -2.0f * b2v; w2sB += b2v;
        }
    const float b2A = b2[netA], b2B = b2[netB];

    float Sreg = S0p[row];                          // register-carried state
    float Vreg = 0.2f;

    __syncthreads();

    // ---- w0f: step-invariant, register-resident for BOTH nets (32 VGPR,
    // deliberate bounded hoist; removes post-barrier ds_read burst) ----
    const uint4* __restrict__ w0ap = &w0a[lane];
    uint4 w0fA[4], w0fB[4];
#pragma unroll
    for (int mt = 0; mt < 4; ++mt) {
        w0fA[mt] = w0ap[(netA * 4 + mt) * 64];
        w0fB[mt] = w0ap[(netB * 4 + mt) * 64];
    }

    const uint4* __restrict__ w1p  = &w1f[lane];
    const float* __restrict__ z1p  = Z1 + path * N_STEPS;
    const float* __restrict__ z2p  = Z2 + path * N_STEPS;
    const bool q0 = (q == 0);

    for (int step = 0; step < N_STEPS; ++step) {
        const float z1 = z1p[step];
        const float z2 = z2p[step];
        const float tA = dta * (float)step;

        // per-step input-frag parts (shared by both phases; no q-masking --
        // W0 A-frag zeros on lanes q!=0 already mask those k-slots)
        float th, tl; bsplit(tA, th, tl);
        const unsigned td2 = cvt_pk_bf16(th, tl);
        const unsigned td3 = cvt_pk_bf16(th, 0.0f);

        // ---- phase 1: my net (role) on (S, V, rf, t) ----
        {
            float sh, sl; bsplit(Sreg, sh, sl);
            u32x4 sv;
            sv[0] = cvt_pk_bf16(sh, sl);
            sv[1] = cvt_pk_bf16(sh, Vreg);
            sv[2] = td2;
            sv[3] = td3;
            const float f = mlp_one(netA, q, __builtin_bit_cast(bf16x8, sv),
                                    w0fA, b0e, w1p, b1k, w2nA, w2sA, b2A);
            if (q0) { if (role == 0) fx2[row].x = f; else fx2[row].y = f; }
        }
        __syncthreads();
        {   // both waves update S redundantly (deterministic, same inputs)
            const float2 fp = fx2[row];
            Sreg = Sreg * fmaf(fp.y, z1, fmaf(fp.x, dta, 1.0f));
        }

        // ---- phase 2: my net (role+2) on (S_new, V, rf, t) ----
        {
            float sh, sl; bsplit(Sreg, sh, sl);
            u32x4 sv;
            sv[0] = cvt_pk_bf16(sh, sl);
            sv[1] = cvt_pk_bf16(sh, Vreg);
            sv[2] = td2;
            sv[3] = td3;
            const float g = mlp_one(netB, q, __builtin_bit_cast(bf16x8, sv),
                                    w0fB, b0e, w1p, b1k, w2nB, w2sB, b2B);
            if (q0) { if (role == 0) gx2[row].x = g; else gx2[row].y = g; }
        }
        __syncthreads();
        {
            const float2 gp = gx2[row];
            Vreg = Vreg * fmaf(gp.y, sqdt * z2, fmaf(gp.x, dta, 1.0f));
        }
    }

    // ---- payoff: one lane per row writes (Sreg in registers, no sync) ----
    if (role == 0 && q == 0) {
        const float Tt   = dta * (float)N_STEPS;
        const float disc = __builtin_amdgcn_exp2f(-rf * Tt * 1.4426950408889634f)
                           * (1.0f / (float)N_PATHS);
        const float Kv = Kp[row];
        const float p1 = (Sreg - Kv < 0.0f) ? 0.0f : Sreg;
        const float v  = disc * p1;
        if (use_ws) ws[path * 64 + row] = v;
        else        atomicAdd(&out[row], v);
    }
}

__global__ void reduce_kernel(const float* __restrict__ ws, float* __restrict__ out) {
    __shared__ float acc[4][64];
    const int o = threadIdx.x & 63, g = threadIdx.x >> 6;
    float s = 0.0f;
    for (int b = g; b < N_PATHS; b += 4) s += ws[b * 64 + o];
    acc[g][o] = s;
    __syncthreads();
    if (threadIdx.x < 64)
        out[threadIdx.x] = acc[0][threadIdx.x] + acc[1][threadIdx.x]
                         + acc[2][threadIdx.x] + acc[3][threadIdx.x];
}

__global__ void zero_out_kernel(float* __restrict__ out) {
    out[threadIdx.x] = 0.0f;
}

extern "C" void kernel_launch(void* const* d_in, const int* in_sizes, int n_in,
                              void* d_out, int out_size, void* d_ws, size_t ws_size,
                              hipStream_t stream) {
    const float* S0p = (const float*)d_in[0];
    const float* Kp  = (const float*)d_in[1];
    const float* Tp  = (const float*)d_in[2];
    const float* rfp = (const float*)d_in[3];
    const float* Z1  = (const float*)d_in[4];
    const float* Z2  = (const float*)d_in[5];
    const float* W0  = (const float*)d_in[6];
    const float* b0  = (const float*)d_in[7];
    const float* W1  = (const float*)d_in[8];
    const float* b1  = (const float*)d_in[9];
    const float* W2  = (const float*)d_in[10];
    const float* b2  = (const float*)d_in[11];
    float* out = (float*)d_out;
    float* wsf = (float*)d_ws;

    const int use_ws = (ws_size >= (size_t)(N_PATHS * 64 * sizeof(float))) ? 1 : 0;

    if (!use_ws) zero_out_kernel<<<1, B_OPTS, 0, stream>>>(out);
    nsde_kernel<<<N_PATHS, 512, 0, stream>>>(S0p, Kp, Tp, rfp, Z1, Z2,
                                             W0, b0, W1, b1, W2, b2, out, wsf, use_ws);
    if (use_ws) reduce_kernel<<<1, 256, 0, stream>>>(wsf, out);
}